// Round 1
// 159.453 us; speedup vs baseline: 1.0852x; 1.0852x over previous
//
#include <hip/hip_runtime.h>
#include <hip/hip_bf16.h>

// Fused QKV projection + 16-head self-attention. S=2048, B=2, H=1024, NH=16, DH=64.
// Inputs fp32, output fp32. bf16 internal compute (2% rel threshold).
//
// R13: attention rebuilt on 32x32x16 MFMA (4x FLOP per LDS-fragment byte vs
// 16x16x32). Swapped QK^T (S^T = K*Q^T) puts a full 32-key slice of one q-row
// in each lane -> softmax fully in-register (exp2 + bf16 pair-pack +
// v_permlane32_swap_b32 redistribution, T12 recipe); the Ptq LDS round-trip is
// gone. Blocks = 4 waves x 32 q = 128 q, so K/V staging amortizes over 2x the
// work. LDS bytes/work drop 2.4x; MFMA instr count halves. GEMM/cast unchanged.
//
// d_ws: qb[hb][s][d] 8MB | kb[hb][s][d] 8MB | vtb[hb][d][s] 8MB  (hb = h*2+b)

typedef __hip_bfloat16 bf16;
typedef __bf16 bfr;
typedef __attribute__((ext_vector_type(8))) __bf16 bf16x8;
typedef __attribute__((ext_vector_type(4))) __bf16 bf16x4;
typedef __attribute__((ext_vector_type(2))) __bf16 bf16x2;
typedef __attribute__((ext_vector_type(4))) float f32x4;
typedef __attribute__((ext_vector_type(16))) float f32x16;
typedef __attribute__((ext_vector_type(4))) unsigned u32x4;

#define S_SEQ  2048
#define HID    1024
#define OUT3   3072
#define NROWS  4096
#define LSTR   72     // attn LDS row stride (bf16): 144 B

#if __has_builtin(__builtin_amdgcn_exp2f)
#define EXP2F(x) __builtin_amdgcn_exp2f(x)
#else
#define EXP2F(x) exp2f(x)
#endif

// q pre-scale: (1/sqrt(64)) * log2(e) -> scores in base-2 domain
#define QSCALE 0.18033688011112042f

// ---------------------------------------------------------------------------
// Fused cast: fp32 -> bf16 for X then W (verified R9/R10).
// ---------------------------------------------------------------------------
__global__ __launch_bounds__(256) void cast_both_kernel(
    const float* __restrict__ X, bfr* __restrict__ Xb,
    const float* __restrict__ W, bfr* __restrict__ Wb)
{
    int bid = blockIdx.x;
    const float* src;
    bfr* dst;
    int lid;
    if (bid < NROWS * HID / 2048) { src = X; dst = Xb; lid = bid; }
    else { src = W; dst = Wb; lid = bid - NROWS * HID / 2048; }
    int gid = lid * 256 + threadIdx.x;
    const float4* s4 = (const float4*)src;
    float4 a = s4[(size_t)gid * 2];
    float4 b = s4[(size_t)gid * 2 + 1];
    bf16x8 v;
    v[0] = (bfr)a.x; v[1] = (bfr)a.y; v[2] = (bfr)a.z; v[3] = (bfr)a.w;
    v[4] = (bfr)b.x; v[5] = (bfr)b.y; v[6] = (bfr)b.z; v[7] = (bfr)b.w;
    *(bf16x8*)(dst + (size_t)gid * 8) = v;
}

// ---------------------------------------------------------------------------
// MFMA GEMM (m97 recipe). Epilogue: qb (pre-scaled), kb stored directly
// (32B-contiguous per 16 lanes); vtb (V^T, the 4KB-stride case) goes through
// an LDS transpose reusing the As/Bs region, then coalesced bf16x8 stores.
// ---------------------------------------------------------------------------
__device__ __forceinline__ void gload_lds16(const void* g, void* l) {
    __builtin_amdgcn_global_load_lds(
        (const __attribute__((address_space(1))) unsigned int*)g,
        (__attribute__((address_space(3))) unsigned int*)l, 16, 0, 0);
}

__global__ __launch_bounds__(256, 3) void qkv_gemm_mfma(
    const bfr* __restrict__ Xb, const bfr* __restrict__ Wb,
    const float* __restrict__ bias,
    bfr* __restrict__ qb, bfr* __restrict__ kb, bfr* __restrict__ vtb)
{
    __shared__ __attribute__((aligned(16))) unsigned char lds_all[32768];
    bfr* As = (bfr*)lds_all;              // 128x64 bf16 = 16384 B
    bfr* Bs = (bfr*)(lds_all + 16384);    // 128x64 bf16 = 16384 B
    bfr* Tr = (bfr*)lds_all;              // epilogue V^T buf: 64 x 144 = 18432 B

    const int o0 = blockIdx.x * 128;
    const int r0 = blockIdx.y * 128;
    const int tid = threadIdx.x;
    const int lane = tid & 63;
    const int w = tid >> 6;
    const int l15 = lane & 15;
    const int quad = lane >> 4;
    const int m0 = (w & 1) * 64;
    const int n0 = (w >> 1) * 64;

    f32x4 acc[4][4];
#pragma unroll
    for (int mi = 0; mi < 4; mi++)
#pragma unroll
        for (int ni = 0; ni < 4; ni++) acc[mi][ni] = {0.f, 0.f, 0.f, 0.f};

    for (int k0 = 0; k0 < HID; k0 += 64) {
#pragma unroll
        for (int i = 0; i < 4; i++) {
            int c = i * 256 + tid;
            int row = c >> 3, c8 = c & 7;
            gload_lds16(Xb + (size_t)(r0 + row) * HID + k0 + c8 * 8, As + c * 8);
            gload_lds16(Wb + (size_t)(o0 + row) * HID + k0 + c8 * 8, Bs + c * 8);
        }
        __syncthreads();

#pragma unroll
        for (int ks = 0; ks < 2; ks++) {
            bf16x8 af[4], bfg[4];
#pragma unroll
            for (int mi = 0; mi < 4; mi++)
                af[mi] = *(const bf16x8*)(As + (m0 + mi * 16 + l15) * 64 + ks * 32 + quad * 8);
#pragma unroll
            for (int ni = 0; ni < 4; ni++)
                bfg[ni] = *(const bf16x8*)(Bs + (n0 + ni * 16 + l15) * 64 + ks * 32 + quad * 8);
#pragma unroll
            for (int mi = 0; mi < 4; mi++)
#pragma unroll
                for (int ni = 0; ni < 4; ni++)
                    acc[mi][ni] = __builtin_amdgcn_mfma_f32_16x16x32_bf16(
                        af[mi], bfg[ni], acc[mi][ni], 0, 0, 0);
        }
        __syncthreads();   // also makes As/Bs safe to reuse as Tr after loop
    }

    // --- epilogue. C/D layout: col=l15, row=quad*4+r.
    // o0%192==0 : cols are q|k only. ==64: waves 2,3 hold the V tile.
    // ==128: waves 0,1 hold the V tile. V tile always spans d 0..63 x gr 0..127.
    const int omod = o0 % 192;
#pragma unroll
    for (int ni = 0; ni < 4; ni++) {
        int cb = o0 + n0 + ni * 16;
        int h = cb / 192;
        int rem = cb % 192;
        int t = rem >> 6;
        int d = (rem & 63) + l15;
        float bv = bias[cb + l15];
        if (t == 2) {
            // stash V^T into LDS: Tr[d][ (grl&1)*72 + (grl>>1) ]
#pragma unroll
            for (int mi = 0; mi < 4; mi++)
#pragma unroll
                for (int r = 0; r < 4; r++) {
                    int grl = m0 + mi * 16 + quad * 4 + r;   // 0..127
                    Tr[(size_t)d * 144 + (grl & 1) * 72 + (grl >> 1)]
                        = (bfr)(acc[mi][ni][r] + bv);
                }
        } else {
#pragma unroll
            for (int mi = 0; mi < 4; mi++)
#pragma unroll
                for (int r = 0; r < 4; r++) {
                    int gr = r0 + m0 + mi * 16 + quad * 4 + r;
                    int s = gr >> 1, b = gr & 1;
                    int hb = h * 2 + b;
                    float val = acc[mi][ni][r] + bv;
                    if (t == 0)
                        qb[((size_t)hb * S_SEQ + s) * 64 + d] = (bfr)(val * QSCALE);
                    else
                        kb[((size_t)hb * S_SEQ + s) * 64 + d] = (bfr)val;
                }
        }
    }
    if (omod != 0) {          // block-uniform: this block produced a V tile
        __syncthreads();      // Tr writes visible
        int ht = (omod == 64) ? (o0 + 64) / 192 : o0 / 192;
        int d = tid >> 2;
        int b = (tid >> 1) & 1;
        int chunk = tid & 1;            // 32-s half
        int s0 = r0 >> 1;               // r0 is a multiple of 128 -> s0 of 64
        int hb = ht * 2 + b;
        const bfr* src = Tr + (size_t)d * 144 + b * 72 + chunk * 32;
        bfr* dstp = vtb + ((size_t)hb * 64 + d) * S_SEQ + s0 + chunk * 32;
#pragma unroll
        for (int j = 0; j < 4; j++)
            *(bf16x8*)(dstp + j * 8) = *(const bf16x8*)(src + j * 8);
    }
}

// ---------------------------------------------------------------------------
// Attention, 32x32x16 MFMA version.
// Block = 4 waves x 32 q = 128 q rows, one hb. Grid (16, 32) = 512 blocks.
// Per kt (64 keys): staged K [key][d] and V^T [d][key] in LDS (double use of
// the same prefetch-reg scheme as R8); per wave:
//   S^T = K*Q^T : A=K rows (lane&31=key, k=d chunk (lane>>5)*8), B=Q^T from
//                 regs (lane&31=q). C/D: col=lane&31=q, row(key)=
//                 (r&3)+8*(r>>2)+4*(lane>>5)  [m74/m101-verified map].
//   softmax in-register: exp2, pair-pack to bf16 (keys are contiguous in
//   reg pairs), v_permlane32_swap_b32 w[a]<->w[a+2] redistributes into the
//   PV B-fragment (col=q, k=key=(lane>>5)*8+j). No P LDS round-trip.
//   O^T += V^T*P^T : A=V^T rows (lane&31=d).
// ---------------------------------------------------------------------------
__device__ __forceinline__ void plswap(unsigned &a, unsigned &b) {
    // new_a[hi] = old_b[partner], new_b[lo] = old_a[partner]
    asm volatile("v_permlane32_swap_b32 %0, %1" : "+v"(a), "+v"(b));
}

__global__ __launch_bounds__(256, 2) void attn32_kernel(
    const bfr* __restrict__ qb, const bfr* __restrict__ kb,
    const bfr* __restrict__ vtb, float* __restrict__ out)
{
    __shared__ __attribute__((aligned(16))) bfr Ks [64 * LSTR];  // [key][d]
    __shared__ __attribute__((aligned(16))) bfr Vts[64 * LSTR];  // [d][key]

    const int qt = blockIdx.x;
    const int hb = blockIdx.y;
    const int h = hb >> 1, b = hb & 1;
    const int tid = threadIdx.x;
    const int lane = tid & 63;
    const int w = tid >> 6;
    const int l31 = lane & 31;
    const int hi = lane >> 5;
    const size_t hboff = (size_t)hb * S_SEQ * 64;

    const int srow0 = tid >> 3;          // staging row (0..31), +32 for p=1
    const int sc8   = tid & 7;           // 16B chunk

    const int qrow = qt * 128 + w * 32 + l31;
    bf16x8 qf[4];                        // B-frags: k=d in [kk*16+hi*8, +8)
#pragma unroll
    for (int kk = 0; kk < 4; kk++)
        qf[kk] = *(const bf16x8*)(qb + hboff + (size_t)qrow * 64 + kk * 16 + hi * 8);

    f32x16 Oacc[2];
#pragma unroll
    for (int dt = 0; dt < 2; dt++)
#pragma unroll
        for (int i = 0; i < 16; i++) Oacc[dt][i] = 0.f;
    float lsum = 0.f;                    // per-lane partial (own keys only)

    // Prefetch tile 0 into registers.
    bf16x8 kr[2], vr[2];
#pragma unroll
    for (int p = 0; p < 2; p++) {
        int row = srow0 + p * 32;
        kr[p] = *(const bf16x8*)(kb + hboff + (size_t)row * 64 + sc8 * 8);
        vr[p] = *(const bf16x8*)(vtb + hboff + (size_t)row * S_SEQ + sc8 * 8);
    }

    for (int kt = 0; kt < 32; kt++) {
        __syncthreads();   // previous compute done reading Ks/Vts
#pragma unroll
        for (int p = 0; p < 2; p++) {
            int row = srow0 + p * 32;
            *(bf16x8*)(Ks  + row * LSTR + sc8 * 8) = kr[p];
            *(bf16x8*)(Vts + row * LSTR + sc8 * 8) = vr[p];
        }
        // Issue next tile's global loads; latency overlaps compute below.
        {
            int ktn = kt + 1 < 32 ? kt + 1 : 31;
#pragma unroll
            for (int p = 0; p < 2; p++) {
                int row = srow0 + p * 32;
                kr[p] = *(const bf16x8*)(kb + hboff + (size_t)(ktn * 64 + row) * 64 + sc8 * 8);
                vr[p] = *(const bf16x8*)(vtb + hboff + (size_t)row * S_SEQ + ktn * 64 + sc8 * 8);
            }
        }
        __syncthreads();   // Ks/Vts visible

        // --- S^T = K Q^T (base-2 domain), 2 key-tiles of 32 ---
        unsigned wds[2][8];   // packed bf16 pairs; w[a] = keys {.,.} per map
        float rs = 0.f;
#pragma unroll
        for (int t = 0; t < 2; t++) {
            f32x16 sc;
#pragma unroll
            for (int i = 0; i < 16; i++) sc[i] = 0.f;
#pragma unroll
            for (int kk = 0; kk < 4; kk++) {
                bf16x8 kf = *(const bf16x8*)(Ks + (t * 32 + l31) * LSTR + kk * 16 + hi * 8);
                sc = __builtin_amdgcn_mfma_f32_32x32x16_bf16(kf, qf[kk], sc, 0, 0, 0);
            }
            // keys(r) = (r&3) + 8*(r>>2) + 4*hi; pairs r=2a,2a+1 are contiguous
#pragma unroll
            for (int a = 0; a < 8; a++) {
                float p0 = EXP2F(sc[2 * a]);
                float p1 = EXP2F(sc[2 * a + 1]);
                rs += p0 + p1;
                bf16x2 pk; pk[0] = (bfr)p0; pk[1] = (bfr)p1;
                wds[t][a] = __builtin_bit_cast(unsigned, pk);
            }
        }
        lsum += rs;

        // --- redistribute into PV B-frags: swap(w[a], w[a+2]) fills two words
        bf16x8 pfrag[4];
#pragma unroll
        for (int c = 0; c < 4; c++) {
            int t = c >> 1, cc = c & 1;
            unsigned w0 = wds[t][cc * 4 + 0];
            unsigned w1 = wds[t][cc * 4 + 1];
            unsigned w2 = wds[t][cc * 4 + 2];
            unsigned w3 = wds[t][cc * 4 + 3];
            plswap(w0, w2);   // -> frag words 0 and 2
            plswap(w1, w3);   // -> frag words 1 and 3
            u32x4 pw; pw[0] = w0; pw[1] = w1; pw[2] = w2; pw[3] = w3;
            pfrag[c] = __builtin_bit_cast(bf16x8, pw);
        }

        // --- O^T += V^T P^T ---
#pragma unroll
        for (int kk = 0; kk < 4; kk++)
#pragma unroll
            for (int dt = 0; dt < 2; dt++) {
                bf16x8 vf = *(const bf16x8*)(Vts + (dt * 32 + l31) * LSTR + kk * 16 + hi * 8);
                Oacc[dt] = __builtin_amdgcn_mfma_f32_32x32x16_bf16(vf, pfrag[kk], Oacc[dt], 0, 0, 0);
            }
    }

    // --- epilogue: O^T[d][q] -> out[s][b][h*64+d], float4 stores ---
    lsum += __shfl_xor(lsum, 32);        // combine the two key-halves
    float inv = 1.0f / lsum;
    float* orow = out + ((size_t)qrow * 2 + b) * HID + h * 64;
#pragma unroll
    for (int dt = 0; dt < 2; dt++)
#pragma unroll
        for (int g = 0; g < 4; g++) {
            float4 o4;
            o4.x = Oacc[dt][4 * g + 0] * inv;
            o4.y = Oacc[dt][4 * g + 1] * inv;
            o4.z = Oacc[dt][4 * g + 2] * inv;
            o4.w = Oacc[dt][4 * g + 3] * inv;
            *(float4*)(orow + dt * 32 + 8 * g + 4 * hi) = o4;
        }
}

// ---------------------------------------------------------------------------
extern "C" void kernel_launch(void* const* d_in, const int* in_sizes, int n_in,
                              void* d_out, int out_size, void* d_ws, size_t ws_size,
                              hipStream_t stream) {
    const float* X    = (const float*)d_in[0];
    const float* W    = (const float*)d_in[1];
    const float* bias = (const float*)d_in[2];
    float* out = (float*)d_out;

    bfr* qb  = (bfr*)d_ws;
    bfr* kb  = qb + (size_t)32 * S_SEQ * 64;
    bfr* vtb = kb + (size_t)32 * S_SEQ * 64;

    // d_out as cast scratch (14.7 MB <= 16.8 MB); attention overwrites it last.
    bfr* Xb = (bfr*)d_out;
    bfr* Wb = Xb + (size_t)NROWS * HID;

    cast_both_kernel<<<(NROWS * HID + OUT3 * HID) / 2048, 256, 0, stream>>>(X, Xb, W, Wb);

    dim3 g1(OUT3 / 128, NROWS / 128);           // 24 x 32 = 768 blocks
    qkv_gemm_mfma<<<g1, 256, 0, stream>>>(Xb, Wb, bias, qb, kb, vtb);

    dim3 g2(S_SEQ / 128, 32);                   // 16 x 32 = 512 blocks
    attn32_kernel<<<g2, 256, 0, stream>>>(qb, kb, vtb, out);
}

// Round 2
// 157.708 us; speedup vs baseline: 1.0972x; 1.0111x over previous
//
#include <hip/hip_runtime.h>
#include <hip/hip_bf16.h>

// Fused QKV projection + 16-head self-attention. S=2048, B=2, H=1024, NH=16, DH=64.
// Inputs fp32, output fp32. bf16 internal compute (2% rel threshold).
//
// R14: attn staging rebuilt on global_load_lds + 4-deep LDS ring + counted
// vmcnt(8) + single raw s_barrier per kt (T3/T4). The reg round-trip, staging
// ds_writes, and both compiler-drained __syncthreads are gone; loads for tile
// kt+2 issue at kt (2 iterations of slack). LDS rows are linear 128B with the
// XOR swizzle slot = chunk ^ (row&7) applied to the GLOBAL source and the
// ds_read address (rule 21: both-sides-or-neither) -- same 16B-slot
// distribution as the old LSTR=72 padding (measured 0 conflicts).
// 4 buffers so the stage target (kt+2) never aliases a straggler's read
// buffer (kt-1): diff 3 != 0 mod 4.
//
// d_ws: qb[hb][s][d] 8MB | kb[hb][s][d] 8MB | vtb[hb][d][s] 8MB  (hb = h*2+b)

typedef __hip_bfloat16 bf16;
typedef __bf16 bfr;
typedef __attribute__((ext_vector_type(8))) __bf16 bf16x8;
typedef __attribute__((ext_vector_type(4))) __bf16 bf16x4;
typedef __attribute__((ext_vector_type(2))) __bf16 bf16x2;
typedef __attribute__((ext_vector_type(4))) float f32x4;
typedef __attribute__((ext_vector_type(16))) float f32x16;
typedef __attribute__((ext_vector_type(4))) unsigned u32x4;

#define S_SEQ  2048
#define HID    1024
#define OUT3   3072
#define NROWS  4096

#if __has_builtin(__builtin_amdgcn_exp2f)
#define EXP2F(x) __builtin_amdgcn_exp2f(x)
#else
#define EXP2F(x) exp2f(x)
#endif

// q pre-scale: (1/sqrt(64)) * log2(e) -> scores in base-2 domain
#define QSCALE 0.18033688011112042f

// ---------------------------------------------------------------------------
// Fused cast: fp32 -> bf16 for X then W (verified R9/R10).
// ---------------------------------------------------------------------------
__global__ __launch_bounds__(256) void cast_both_kernel(
    const float* __restrict__ X, bfr* __restrict__ Xb,
    const float* __restrict__ W, bfr* __restrict__ Wb)
{
    int bid = blockIdx.x;
    const float* src;
    bfr* dst;
    int lid;
    if (bid < NROWS * HID / 2048) { src = X; dst = Xb; lid = bid; }
    else { src = W; dst = Wb; lid = bid - NROWS * HID / 2048; }
    int gid = lid * 256 + threadIdx.x;
    const float4* s4 = (const float4*)src;
    float4 a = s4[(size_t)gid * 2];
    float4 b = s4[(size_t)gid * 2 + 1];
    bf16x8 v;
    v[0] = (bfr)a.x; v[1] = (bfr)a.y; v[2] = (bfr)a.z; v[3] = (bfr)a.w;
    v[4] = (bfr)b.x; v[5] = (bfr)b.y; v[6] = (bfr)b.z; v[7] = (bfr)b.w;
    *(bf16x8*)(dst + (size_t)gid * 8) = v;
}

// ---------------------------------------------------------------------------
// MFMA GEMM (m97 recipe). Epilogue: qb (pre-scaled), kb stored directly
// (32B-contiguous per 16 lanes); vtb (V^T, the 4KB-stride case) goes through
// an LDS transpose reusing the As/Bs region, then coalesced bf16x8 stores.
// ---------------------------------------------------------------------------
__device__ __forceinline__ void gload_lds16(const void* g, void* l) {
    __builtin_amdgcn_global_load_lds(
        (const __attribute__((address_space(1))) unsigned int*)g,
        (__attribute__((address_space(3))) unsigned int*)l, 16, 0, 0);
}

__global__ __launch_bounds__(256, 3) void qkv_gemm_mfma(
    const bfr* __restrict__ Xb, const bfr* __restrict__ Wb,
    const float* __restrict__ bias,
    bfr* __restrict__ qb, bfr* __restrict__ kb, bfr* __restrict__ vtb)
{
    __shared__ __attribute__((aligned(16))) unsigned char lds_all[32768];
    bfr* As = (bfr*)lds_all;              // 128x64 bf16 = 16384 B
    bfr* Bs = (bfr*)(lds_all + 16384);    // 128x64 bf16 = 16384 B
    bfr* Tr = (bfr*)lds_all;              // epilogue V^T buf: 64 x 144 = 18432 B

    const int o0 = blockIdx.x * 128;
    const int r0 = blockIdx.y * 128;
    const int tid = threadIdx.x;
    const int lane = tid & 63;
    const int w = tid >> 6;
    const int l15 = lane & 15;
    const int quad = lane >> 4;
    const int m0 = (w & 1) * 64;
    const int n0 = (w >> 1) * 64;

    f32x4 acc[4][4];
#pragma unroll
    for (int mi = 0; mi < 4; mi++)
#pragma unroll
        for (int ni = 0; ni < 4; ni++) acc[mi][ni] = {0.f, 0.f, 0.f, 0.f};

    for (int k0 = 0; k0 < HID; k0 += 64) {
#pragma unroll
        for (int i = 0; i < 4; i++) {
            int c = i * 256 + tid;
            int row = c >> 3, c8 = c & 7;
            gload_lds16(Xb + (size_t)(r0 + row) * HID + k0 + c8 * 8, As + c * 8);
            gload_lds16(Wb + (size_t)(o0 + row) * HID + k0 + c8 * 8, Bs + c * 8);
        }
        __syncthreads();

#pragma unroll
        for (int ks = 0; ks < 2; ks++) {
            bf16x8 af[4], bfg[4];
#pragma unroll
            for (int mi = 0; mi < 4; mi++)
                af[mi] = *(const bf16x8*)(As + (m0 + mi * 16 + l15) * 64 + ks * 32 + quad * 8);
#pragma unroll
            for (int ni = 0; ni < 4; ni++)
                bfg[ni] = *(const bf16x8*)(Bs + (n0 + ni * 16 + l15) * 64 + ks * 32 + quad * 8);
#pragma unroll
            for (int mi = 0; mi < 4; mi++)
#pragma unroll
                for (int ni = 0; ni < 4; ni++)
                    acc[mi][ni] = __builtin_amdgcn_mfma_f32_16x16x32_bf16(
                        af[mi], bfg[ni], acc[mi][ni], 0, 0, 0);
        }
        __syncthreads();   // also makes As/Bs safe to reuse as Tr after loop
    }

    // --- epilogue. C/D layout: col=l15, row=quad*4+r.
    // o0%192==0 : cols are q|k only. ==64: waves 2,3 hold the V tile.
    // ==128: waves 0,1 hold the V tile. V tile always spans d 0..63 x gr 0..127.
    const int omod = o0 % 192;
#pragma unroll
    for (int ni = 0; ni < 4; ni++) {
        int cb = o0 + n0 + ni * 16;
        int h = cb / 192;
        int rem = cb % 192;
        int t = rem >> 6;
        int d = (rem & 63) + l15;
        float bv = bias[cb + l15];
        if (t == 2) {
            // stash V^T into LDS: Tr[d][ (grl&1)*72 + (grl>>1) ]
#pragma unroll
            for (int mi = 0; mi < 4; mi++)
#pragma unroll
                for (int r = 0; r < 4; r++) {
                    int grl = m0 + mi * 16 + quad * 4 + r;   // 0..127
                    Tr[(size_t)d * 144 + (grl & 1) * 72 + (grl >> 1)]
                        = (bfr)(acc[mi][ni][r] + bv);
                }
        } else {
#pragma unroll
            for (int mi = 0; mi < 4; mi++)
#pragma unroll
                for (int r = 0; r < 4; r++) {
                    int gr = r0 + m0 + mi * 16 + quad * 4 + r;
                    int s = gr >> 1, b = gr & 1;
                    int hb = h * 2 + b;
                    float val = acc[mi][ni][r] + bv;
                    if (t == 0)
                        qb[((size_t)hb * S_SEQ + s) * 64 + d] = (bfr)(val * QSCALE);
                    else
                        kb[((size_t)hb * S_SEQ + s) * 64 + d] = (bfr)val;
                }
        }
    }
    if (omod != 0) {          // block-uniform: this block produced a V tile
        __syncthreads();      // Tr writes visible
        int ht = (omod == 64) ? (o0 + 64) / 192 : o0 / 192;
        int d = tid >> 2;
        int b = (tid >> 1) & 1;
        int chunk = tid & 1;            // 32-s half
        int s0 = r0 >> 1;               // r0 is a multiple of 128 -> s0 of 64
        int hb = ht * 2 + b;
        const bfr* src = Tr + (size_t)d * 144 + b * 72 + chunk * 32;
        bfr* dstp = vtb + ((size_t)hb * 64 + d) * S_SEQ + s0 + chunk * 32;
#pragma unroll
        for (int j = 0; j < 4; j++)
            *(bf16x8*)(dstp + j * 8) = *(const bf16x8*)(src + j * 8);
    }
}

// ---------------------------------------------------------------------------
// Attention, 32x32x16 MFMA + gload_lds 4-deep pipeline.
// Block = 4 waves x 32 q = 128 q rows, one hb. Grid (16, 32) = 512 blocks.
//   S^T = K*Q^T : A=K rows (lane&31=key), B=Q^T regs (lane&31=q).
//   C/D: col=lane&31=q, row(key)=(r&3)+8*(r>>2)+4*(lane>>5).
//   softmax in-register: exp2 + bf16 pair-pack + v_permlane32_swap_b32.
//   O^T += V^T*P^T : A=V^T rows (lane&31=d).
// LDS: ring of 4 x {K[64][64], V^T[64][64]} bf16, linear 128B rows; XOR
// swizzle slot = chunk16B ^ (row&7) applied at the global source (staging)
// and at the ds_read address (compute).
// ---------------------------------------------------------------------------
__device__ __forceinline__ void plswap(unsigned &a, unsigned &b) {
    asm volatile("v_permlane32_swap_b32 %0, %1" : "+v"(a), "+v"(b));
}

__global__ __launch_bounds__(256, 2) void attn32_kernel(
    const bfr* __restrict__ qb, const bfr* __restrict__ kb,
    const bfr* __restrict__ vtb, float* __restrict__ out)
{
    // [buf][K=0/V=1][row*64 + elem]; 4 * 2 * 8KB = 64KB
    __shared__ __attribute__((aligned(16))) bfr KV[4][2][64 * 64];

    const int qt = blockIdx.x;
    const int hb = blockIdx.y;
    const int h = hb >> 1, b = hb & 1;
    const int tid = threadIdx.x;
    const int lane = tid & 63;
    const int w = tid >> 6;
    const int l31 = lane & 31;
    const int hi = lane >> 5;
    const size_t hboff = (size_t)hb * S_SEQ * 64;

    const int srow = tid >> 3;           // staging row (0..31), +32 for i=1
    const int slot = tid & 7;            // 16B slot within the 128B row

    const int qrow = qt * 128 + w * 32 + l31;
    bf16x8 qf[4];                        // B-frags: k=d in [kk*16+hi*8, +8)
#pragma unroll
    for (int kk = 0; kk < 4; kk++)
        qf[kk] = *(const bf16x8*)(qb + hboff + (size_t)qrow * 64 + kk * 16 + hi * 8);

    f32x16 Oacc[2];
#pragma unroll
    for (int dt = 0; dt < 2; dt++)
#pragma unroll
        for (int i = 0; i < 16; i++) Oacc[dt][i] = 0.f;
    float lsum = 0.f;                    // per-lane partial (own keys only)

    // Stage tile kt into ring buffer buf. 4 gload_lds per thread (2 K, 2 V).
    // LDS dest is linear (i*4KB + tid*16B == row*128 + slot*16); the global
    // chunk fetched is gc = slot ^ (row&7)  (inverse-swizzled source).
#define STAGE(kt_, buf_) do {                                                  \
    int kt__ = (kt_); int bf__ = (buf_);                                       \
    _Pragma("unroll")                                                          \
    for (int i = 0; i < 2; i++) {                                              \
        int r = i * 32 + srow;                                                 \
        int gc = slot ^ (r & 7);                                               \
        gload_lds16(kb + hboff + (size_t)(kt__ * 64 + r) * 64 + gc * 8,        \
                    (bfr*)&KV[bf__][0][0] + i * 2048 + tid * 8);               \
    }                                                                          \
    _Pragma("unroll")                                                          \
    for (int i = 0; i < 2; i++) {                                              \
        int r = i * 32 + srow;                                                 \
        int gc = slot ^ (r & 7);                                               \
        gload_lds16(vtb + hboff + (size_t)r * S_SEQ + kt__ * 64 + gc * 8,      \
                    (bfr*)&KV[bf__][1][0] + i * 2048 + tid * 8);               \
    }                                                                          \
} while (0)

    STAGE(0, 0);
    STAGE(1, 1);

    for (int kt = 0; kt < 32; kt++) {
        // Issue tile kt+2 (dummy re-stage of 31 at the tail keeps vmcnt
        // bookkeeping constant; targets buffers never read again).
        {
            int ktn = (kt + 2 <= 31) ? kt + 2 : 31;
            STAGE(ktn, (kt + 2) & 3);
        }
        // Outstanding per wave: stage(kt+1)=4 + stage(kt+2)=4. vmcnt(8)
        // guarantees MY stage(kt) landed; the barrier extends that to all
        // waves (everyone executes the same wait).
        asm volatile("s_waitcnt vmcnt(8)" ::: "memory");
        __builtin_amdgcn_s_barrier();

        const bfr* Kb = &KV[kt & 3][0][0];
        const bfr* Vb = &KV[kt & 3][1][0];

        // --- S^T = K Q^T (base-2 domain), 2 key-tiles of 32 ---
        unsigned wds[2][8];   // packed bf16 pairs
        float rs = 0.f;
#pragma unroll
        for (int t = 0; t < 2; t++) {
            f32x16 sc;
#pragma unroll
            for (int i = 0; i < 16; i++) sc[i] = 0.f;
#pragma unroll
            for (int kk = 0; kk < 4; kk++) {
                int krow = t * 32 + l31;
                int ks = (kk * 2 + hi) ^ (krow & 7);
                bf16x8 kf = *(const bf16x8*)(Kb + krow * 64 + ks * 8);
                sc = __builtin_amdgcn_mfma_f32_32x32x16_bf16(kf, qf[kk], sc, 0, 0, 0);
            }
            // keys(r) = (r&3) + 8*(r>>2) + 4*hi; pairs r=2a,2a+1 contiguous
#pragma unroll
            for (int a = 0; a < 8; a++) {
                float p0 = EXP2F(sc[2 * a]);
                float p1 = EXP2F(sc[2 * a + 1]);
                rs += p0 + p1;
                bf16x2 pk; pk[0] = (bfr)p0; pk[1] = (bfr)p1;
                wds[t][a] = __builtin_bit_cast(unsigned, pk);
            }
        }
        lsum += rs;

        // --- redistribute into PV B-frags: swap(w[a], w[a+2]) fills two words
        bf16x8 pfrag[4];
#pragma unroll
        for (int c = 0; c < 4; c++) {
            int t = c >> 1, cc = c & 1;
            unsigned w0 = wds[t][cc * 4 + 0];
            unsigned w1 = wds[t][cc * 4 + 1];
            unsigned w2 = wds[t][cc * 4 + 2];
            unsigned w3 = wds[t][cc * 4 + 3];
            plswap(w0, w2);   // -> frag words 0 and 2
            plswap(w1, w3);   // -> frag words 1 and 3
            u32x4 pw; pw[0] = w0; pw[1] = w1; pw[2] = w2; pw[3] = w3;
            pfrag[c] = __builtin_bit_cast(bf16x8, pw);
        }

        // --- O^T += V^T P^T ---
#pragma unroll
        for (int kk = 0; kk < 4; kk++)
#pragma unroll
            for (int dt = 0; dt < 2; dt++) {
                int vrow = dt * 32 + l31;
                int vs = (kk * 2 + hi) ^ (vrow & 7);
                bf16x8 vf = *(const bf16x8*)(Vb + vrow * 64 + vs * 8);
                Oacc[dt] = __builtin_amdgcn_mfma_f32_32x32x16_bf16(vf, pfrag[kk], Oacc[dt], 0, 0, 0);
            }
    }
#undef STAGE

    // --- epilogue: O^T[d][q] -> out[s][b][h*64+d], float4 stores ---
    lsum += __shfl_xor(lsum, 32);        // combine the two key-halves
    float inv = 1.0f / lsum;
    float* orow = out + ((size_t)qrow * 2 + b) * HID + h * 64;
#pragma unroll
    for (int dt = 0; dt < 2; dt++)
#pragma unroll
        for (int g = 0; g < 4; g++) {
            float4 o4;
            o4.x = Oacc[dt][4 * g + 0] * inv;
            o4.y = Oacc[dt][4 * g + 1] * inv;
            o4.z = Oacc[dt][4 * g + 2] * inv;
            o4.w = Oacc[dt][4 * g + 3] * inv;
            *(float4*)(orow + dt * 32 + 8 * g + 4 * hi) = o4;
        }
}

// ---------------------------------------------------------------------------
extern "C" void kernel_launch(void* const* d_in, const int* in_sizes, int n_in,
                              void* d_out, int out_size, void* d_ws, size_t ws_size,
                              hipStream_t stream) {
    const float* X    = (const float*)d_in[0];
    const float* W    = (const float*)d_in[1];
    const float* bias = (const float*)d_in[2];
    float* out = (float*)d_out;

    bfr* qb  = (bfr*)d_ws;
    bfr* kb  = qb + (size_t)32 * S_SEQ * 64;
    bfr* vtb = kb + (size_t)32 * S_SEQ * 64;

    // d_out as cast scratch (14.7 MB <= 16.8 MB); attention overwrites it last.
    bfr* Xb = (bfr*)d_out;
    bfr* Wb = Xb + (size_t)NROWS * HID;

    cast_both_kernel<<<(NROWS * HID + OUT3 * HID) / 2048, 256, 0, stream>>>(X, Xb, W, Wb);

    dim3 g1(OUT3 / 128, NROWS / 128);           // 24 x 32 = 768 blocks
    qkv_gemm_mfma<<<g1, 256, 0, stream>>>(Xb, Wb, bias, qb, kb, vtb);

    dim3 g2(S_SEQ / 128, 32);                   // 16 x 32 = 512 blocks
    attn32_kernel<<<g2, 256, 0, stream>>>(qb, kb, vtb, out);
}

// Round 3
// 154.891 us; speedup vs baseline: 1.1171x; 1.0182x over previous
//
#include <hip/hip_runtime.h>
#include <hip/hip_bf16.h>

// Fused QKV projection + 16-head self-attention. S=2048, B=2, H=1024, NH=16, DH=64.
// Inputs fp32, output fp32. bf16 internal compute (2% rel threshold).
//
// R15: attn iterates KVBLK=128 (two 64-key tiles) per barrier phase: 16 iters
// instead of 32 -> half the barrier/wait fixed costs, 2x independent MFMA
// chains per phase (4 QK chains, softmax of one sub-tile overlaps MFMA of the
// other). Staging is stage-AFTER-barrier into the 4x16KB ring: the barrier
// that releases compute(i) also proves all reads of stage(i+1)'s target
// buffers finished, and vmcnt(0) then waits on loads issued a full compute
// phase ago (slack >> HBM latency -> no stall; T4 restated as issue-to-wait
// slack). T5 s_setprio(1) wraps the MFMA clusters. Tail dummy-stages gone.
// Parallelism is structurally capped at 2 waves/SIMD (2048 waves total), so
// this round attacks per-iteration latency, not occupancy.
//
// d_ws: qb[hb][s][d] 8MB | kb[hb][s][d] 8MB | vtb[hb][d][s] 8MB  (hb = h*2+b)

typedef __hip_bfloat16 bf16;
typedef __bf16 bfr;
typedef __attribute__((ext_vector_type(8))) __bf16 bf16x8;
typedef __attribute__((ext_vector_type(4))) __bf16 bf16x4;
typedef __attribute__((ext_vector_type(2))) __bf16 bf16x2;
typedef __attribute__((ext_vector_type(4))) float f32x4;
typedef __attribute__((ext_vector_type(16))) float f32x16;
typedef __attribute__((ext_vector_type(4))) unsigned u32x4;

#define S_SEQ  2048
#define HID    1024
#define OUT3   3072
#define NROWS  4096

#if __has_builtin(__builtin_amdgcn_exp2f)
#define EXP2F(x) __builtin_amdgcn_exp2f(x)
#else
#define EXP2F(x) exp2f(x)
#endif

// q pre-scale: (1/sqrt(64)) * log2(e) -> scores in base-2 domain
#define QSCALE 0.18033688011112042f

// ---------------------------------------------------------------------------
// Fused cast: fp32 -> bf16 for X then W (verified R9/R10).
// ---------------------------------------------------------------------------
__global__ __launch_bounds__(256) void cast_both_kernel(
    const float* __restrict__ X, bfr* __restrict__ Xb,
    const float* __restrict__ W, bfr* __restrict__ Wb)
{
    int bid = blockIdx.x;
    const float* src;
    bfr* dst;
    int lid;
    if (bid < NROWS * HID / 2048) { src = X; dst = Xb; lid = bid; }
    else { src = W; dst = Wb; lid = bid - NROWS * HID / 2048; }
    int gid = lid * 256 + threadIdx.x;
    const float4* s4 = (const float4*)src;
    float4 a = s4[(size_t)gid * 2];
    float4 b = s4[(size_t)gid * 2 + 1];
    bf16x8 v;
    v[0] = (bfr)a.x; v[1] = (bfr)a.y; v[2] = (bfr)a.z; v[3] = (bfr)a.w;
    v[4] = (bfr)b.x; v[5] = (bfr)b.y; v[6] = (bfr)b.z; v[7] = (bfr)b.w;
    *(bf16x8*)(dst + (size_t)gid * 8) = v;
}

// ---------------------------------------------------------------------------
// MFMA GEMM (m97 recipe). Epilogue: qb (pre-scaled), kb stored directly
// (32B-contiguous per 16 lanes); vtb (V^T, the 4KB-stride case) goes through
// an LDS transpose reusing the As/Bs region, then coalesced bf16x8 stores.
// ---------------------------------------------------------------------------
__device__ __forceinline__ void gload_lds16(const void* g, void* l) {
    __builtin_amdgcn_global_load_lds(
        (const __attribute__((address_space(1))) unsigned int*)g,
        (__attribute__((address_space(3))) unsigned int*)l, 16, 0, 0);
}

__global__ __launch_bounds__(256, 3) void qkv_gemm_mfma(
    const bfr* __restrict__ Xb, const bfr* __restrict__ Wb,
    const float* __restrict__ bias,
    bfr* __restrict__ qb, bfr* __restrict__ kb, bfr* __restrict__ vtb)
{
    __shared__ __attribute__((aligned(16))) unsigned char lds_all[32768];
    bfr* As = (bfr*)lds_all;              // 128x64 bf16 = 16384 B
    bfr* Bs = (bfr*)(lds_all + 16384);    // 128x64 bf16 = 16384 B
    bfr* Tr = (bfr*)lds_all;              // epilogue V^T buf: 64 x 144 = 18432 B

    const int o0 = blockIdx.x * 128;
    const int r0 = blockIdx.y * 128;
    const int tid = threadIdx.x;
    const int lane = tid & 63;
    const int w = tid >> 6;
    const int l15 = lane & 15;
    const int quad = lane >> 4;
    const int m0 = (w & 1) * 64;
    const int n0 = (w >> 1) * 64;

    f32x4 acc[4][4];
#pragma unroll
    for (int mi = 0; mi < 4; mi++)
#pragma unroll
        for (int ni = 0; ni < 4; ni++) acc[mi][ni] = {0.f, 0.f, 0.f, 0.f};

    for (int k0 = 0; k0 < HID; k0 += 64) {
#pragma unroll
        for (int i = 0; i < 4; i++) {
            int c = i * 256 + tid;
            int row = c >> 3, c8 = c & 7;
            gload_lds16(Xb + (size_t)(r0 + row) * HID + k0 + c8 * 8, As + c * 8);
            gload_lds16(Wb + (size_t)(o0 + row) * HID + k0 + c8 * 8, Bs + c * 8);
        }
        __syncthreads();

#pragma unroll
        for (int ks = 0; ks < 2; ks++) {
            bf16x8 af[4], bfg[4];
#pragma unroll
            for (int mi = 0; mi < 4; mi++)
                af[mi] = *(const bf16x8*)(As + (m0 + mi * 16 + l15) * 64 + ks * 32 + quad * 8);
#pragma unroll
            for (int ni = 0; ni < 4; ni++)
                bfg[ni] = *(const bf16x8*)(Bs + (n0 + ni * 16 + l15) * 64 + ks * 32 + quad * 8);
#pragma unroll
            for (int mi = 0; mi < 4; mi++)
#pragma unroll
                for (int ni = 0; ni < 4; ni++)
                    acc[mi][ni] = __builtin_amdgcn_mfma_f32_16x16x32_bf16(
                        af[mi], bfg[ni], acc[mi][ni], 0, 0, 0);
        }
        __syncthreads();   // also makes As/Bs safe to reuse as Tr after loop
    }

    // --- epilogue. C/D layout: col=l15, row=quad*4+r.
    // o0%192==0 : cols are q|k only. ==64: waves 2,3 hold the V tile.
    // ==128: waves 0,1 hold the V tile. V tile always spans d 0..63 x gr 0..127.
    const int omod = o0 % 192;
#pragma unroll
    for (int ni = 0; ni < 4; ni++) {
        int cb = o0 + n0 + ni * 16;
        int h = cb / 192;
        int rem = cb % 192;
        int t = rem >> 6;
        int d = (rem & 63) + l15;
        float bv = bias[cb + l15];
        if (t == 2) {
            // stash V^T into LDS: Tr[d][ (grl&1)*72 + (grl>>1) ]
#pragma unroll
            for (int mi = 0; mi < 4; mi++)
#pragma unroll
                for (int r = 0; r < 4; r++) {
                    int grl = m0 + mi * 16 + quad * 4 + r;   // 0..127
                    Tr[(size_t)d * 144 + (grl & 1) * 72 + (grl >> 1)]
                        = (bfr)(acc[mi][ni][r] + bv);
                }
        } else {
#pragma unroll
            for (int mi = 0; mi < 4; mi++)
#pragma unroll
                for (int r = 0; r < 4; r++) {
                    int gr = r0 + m0 + mi * 16 + quad * 4 + r;
                    int s = gr >> 1, b = gr & 1;
                    int hb = h * 2 + b;
                    float val = acc[mi][ni][r] + bv;
                    if (t == 0)
                        qb[((size_t)hb * S_SEQ + s) * 64 + d] = (bfr)(val * QSCALE);
                    else
                        kb[((size_t)hb * S_SEQ + s) * 64 + d] = (bfr)val;
                }
        }
    }
    if (omod != 0) {          // block-uniform: this block produced a V tile
        __syncthreads();      // Tr writes visible
        int ht = (omod == 64) ? (o0 + 64) / 192 : o0 / 192;
        int d = tid >> 2;
        int b = (tid >> 1) & 1;
        int chunk = tid & 1;            // 32-s half
        int s0 = r0 >> 1;               // r0 is a multiple of 128 -> s0 of 64
        int hb = ht * 2 + b;
        const bfr* src = Tr + (size_t)d * 144 + b * 72 + chunk * 32;
        bfr* dstp = vtb + ((size_t)hb * 64 + d) * S_SEQ + s0 + chunk * 32;
#pragma unroll
        for (int j = 0; j < 4; j++)
            *(bf16x8*)(dstp + j * 8) = *(const bf16x8*)(src + j * 8);
    }
}

// ---------------------------------------------------------------------------
// Attention, 32x32x16 MFMA, KVBLK=128 per phase, gload_lds 4x16KB ring.
// Block = 4 waves x 32 q = 128 q rows, one hb. Grid (16, 32) = 512 blocks.
//   S^T = K*Q^T : A=K rows (lane&31=key), B=Q^T regs (lane&31=q).
//   C/D: col=lane&31=q, row(key)=(r&3)+8*(r>>2)+4*(lane>>5).
//   softmax in-register: exp2 + bf16 pair-pack + v_permlane32_swap_b32.
//   O^T += V^T*P^T : A=V^T rows (lane&31=d).
// LDS: ring of 4 x {K[64][64], V^T[64][64]} bf16 (tile t -> buf t&3), linear
// 128B rows; XOR swizzle slot = chunk16B ^ (row&7) applied at the global
// source (staging) and the ds_read address (compute) -- rule 21.
// Schedule per iter i (tiles 2i, 2i+1):
//   vmcnt(0)              // tiles 2i,2i+1 landed; issued one full phase ago
//   s_barrier             // + proves all reads of bufs (2i+2)&3,(2i+3)&3 done
//   STAGE(2i+2); STAGE(2i+3)   // async, lands during compute below
//   QK(4 chains) -> softmax -> PV(16 MFMA)
// ---------------------------------------------------------------------------
__device__ __forceinline__ void plswap(unsigned &a, unsigned &b) {
    asm volatile("v_permlane32_swap_b32 %0, %1" : "+v"(a), "+v"(b));
}

__global__ __launch_bounds__(256, 2) void attn32_kernel(
    const bfr* __restrict__ qb, const bfr* __restrict__ kb,
    const bfr* __restrict__ vtb, float* __restrict__ out)
{
    // [buf][K=0/V=1][row*64 + elem]; 4 * 2 * 8KB = 64KB
    __shared__ __attribute__((aligned(16))) bfr KV[4][2][64 * 64];

    const int qt = blockIdx.x;
    const int hb = blockIdx.y;
    const int h = hb >> 1, b = hb & 1;
    const int tid = threadIdx.x;
    const int lane = tid & 63;
    const int w = tid >> 6;
    const int l31 = lane & 31;
    const int hi = lane >> 5;
    const size_t hboff = (size_t)hb * S_SEQ * 64;

    const int srow = tid >> 3;           // staging row (0..31), +32 for i=1
    const int slot = tid & 7;            // 16B slot within the 128B row

    const int qrow = qt * 128 + w * 32 + l31;
    bf16x8 qf[4];                        // B-frags: k=d in [kk*16+hi*8, +8)
#pragma unroll
    for (int kk = 0; kk < 4; kk++)
        qf[kk] = *(const bf16x8*)(qb + hboff + (size_t)qrow * 64 + kk * 16 + hi * 8);

    f32x16 Oacc[2];
#pragma unroll
    for (int dt = 0; dt < 2; dt++)
#pragma unroll
        for (int i = 0; i < 16; i++) Oacc[dt][i] = 0.f;
    float lsum = 0.f;                    // per-lane partial (own keys only)

    // Stage tile kt into ring buffer kt&3. 4 gload_lds per thread (2 K, 2 V).
    // LDS dest is linear (i*4KB + tid*16B == row*128 + slot*16); the global
    // chunk fetched is gc = slot ^ (row&7)  (inverse-swizzled source).
#define STAGE(kt_) do {                                                        \
    int kt__ = (kt_); int bf__ = kt__ & 3;                                     \
    _Pragma("unroll")                                                          \
    for (int i = 0; i < 2; i++) {                                              \
        int r = i * 32 + srow;                                                 \
        int gc = slot ^ (r & 7);                                               \
        gload_lds16(kb + hboff + (size_t)(kt__ * 64 + r) * 64 + gc * 8,        \
                    (bfr*)&KV[bf__][0][0] + i * 2048 + tid * 8);               \
    }                                                                          \
    _Pragma("unroll")                                                          \
    for (int i = 0; i < 2; i++) {                                              \
        int r = i * 32 + srow;                                                 \
        int gc = slot ^ (r & 7);                                               \
        gload_lds16(vtb + hboff + (size_t)r * S_SEQ + kt__ * 64 + gc * 8,      \
                    (bfr*)&KV[bf__][1][0] + i * 2048 + tid * 8);               \
    }                                                                          \
} while (0)

    STAGE(0);
    STAGE(1);

    for (int it = 0; it < 16; it++) {
        const int t0 = 2 * it;           // first 64-key tile of this phase
        // Loads for tiles t0,t0+1 were issued one full compute phase ago
        // (prologue for it=0): vmcnt(0) waits on nothing in steady state.
        asm volatile("s_waitcnt vmcnt(0)" ::: "memory");
        __builtin_amdgcn_s_barrier();
        if (it < 15) { STAGE(t0 + 2); STAGE(t0 + 3); }

        // --- S^T = K Q^T (base-2 domain), 4 independent key-subtiles of 32 ---
        unsigned wds[4][8];   // packed bf16 pairs
        float rs = 0.f;
#pragma unroll
        for (int t = 0; t < 4; t++) {
            const bfr* Kb = &KV[(t0 + (t >> 1)) & 3][0][0];
            const int krow = (t & 1) * 32 + l31;
            f32x16 sc;
#pragma unroll
            for (int i = 0; i < 16; i++) sc[i] = 0.f;
            __builtin_amdgcn_s_setprio(1);
#pragma unroll
            for (int kk = 0; kk < 4; kk++) {
                int ks = (kk * 2 + hi) ^ (krow & 7);
                bf16x8 kf = *(const bf16x8*)(Kb + krow * 64 + ks * 8);
                sc = __builtin_amdgcn_mfma_f32_32x32x16_bf16(kf, qf[kk], sc, 0, 0, 0);
            }
            __builtin_amdgcn_s_setprio(0);
            // keys(r) = (r&3) + 8*(r>>2) + 4*hi; pairs r=2a,2a+1 contiguous
#pragma unroll
            for (int a = 0; a < 8; a++) {
                float p0 = EXP2F(sc[2 * a]);
                float p1 = EXP2F(sc[2 * a + 1]);
                rs += p0 + p1;
                bf16x2 pk; pk[0] = (bfr)p0; pk[1] = (bfr)p1;
                wds[t][a] = __builtin_bit_cast(unsigned, pk);
            }
        }
        lsum += rs;

        // --- redistribute into PV B-frags: swap(w[a], w[a+2]) fills two words
        bf16x8 pfrag[8];
#pragma unroll
        for (int c = 0; c < 8; c++) {
            int t = c >> 1, cc = c & 1;
            unsigned w0 = wds[t][cc * 4 + 0];
            unsigned w1 = wds[t][cc * 4 + 1];
            unsigned w2 = wds[t][cc * 4 + 2];
            unsigned w3 = wds[t][cc * 4 + 3];
            plswap(w0, w2);   // -> frag words 0 and 2
            plswap(w1, w3);   // -> frag words 1 and 3
            u32x4 pw; pw[0] = w0; pw[1] = w1; pw[2] = w2; pw[3] = w3;
            pfrag[c] = __builtin_bit_cast(bf16x8, pw);
        }

        // --- O^T += V^T P^T  (pfrag[kk] keys match vf columns: 16-block
        //     decomposition (tile kk>>2, 32-half (kk>>1)&1, 16-sub kk&1)) ---
        __builtin_amdgcn_s_setprio(1);
#pragma unroll
        for (int kk = 0; kk < 8; kk++) {
            const bfr* Vb = &KV[(t0 + (kk >> 2)) & 3][1][0];
            const int kkl = kk & 3;
#pragma unroll
            for (int dt = 0; dt < 2; dt++) {
                int vrow = dt * 32 + l31;
                int vs = (kkl * 2 + hi) ^ (vrow & 7);
                bf16x8 vf = *(const bf16x8*)(Vb + vrow * 64 + vs * 8);
                Oacc[dt] = __builtin_amdgcn_mfma_f32_32x32x16_bf16(vf, pfrag[kk], Oacc[dt], 0, 0, 0);
            }
        }
        __builtin_amdgcn_s_setprio(0);
    }
#undef STAGE

    // --- epilogue: O^T[d][q] -> out[s][b][h*64+d], float4 stores ---
    lsum += __shfl_xor(lsum, 32);        // combine the two key-halves
    float inv = 1.0f / lsum;
    float* orow = out + ((size_t)qrow * 2 + b) * HID + h * 64;
#pragma unroll
    for (int dt = 0; dt < 2; dt++)
#pragma unroll
        for (int g = 0; g < 4; g++) {
            float4 o4;
            o4.x = Oacc[dt][4 * g + 0] * inv;
            o4.y = Oacc[dt][4 * g + 1] * inv;
            o4.z = Oacc[dt][4 * g + 2] * inv;
            o4.w = Oacc[dt][4 * g + 3] * inv;
            *(float4*)(orow + dt * 32 + 8 * g + 4 * hi) = o4;
        }
}

// ---------------------------------------------------------------------------
extern "C" void kernel_launch(void* const* d_in, const int* in_sizes, int n_in,
                              void* d_out, int out_size, void* d_ws, size_t ws_size,
                              hipStream_t stream) {
    const float* X    = (const float*)d_in[0];
    const float* W    = (const float*)d_in[1];
    const float* bias = (const float*)d_in[2];
    float* out = (float*)d_out;

    bfr* qb  = (bfr*)d_ws;
    bfr* kb  = qb + (size_t)32 * S_SEQ * 64;
    bfr* vtb = kb + (size_t)32 * S_SEQ * 64;

    // d_out as cast scratch (14.7 MB <= 16.8 MB); attention overwrites it last.
    bfr* Xb = (bfr*)d_out;
    bfr* Wb = Xb + (size_t)NROWS * HID;

    cast_both_kernel<<<(NROWS * HID + OUT3 * HID) / 2048, 256, 0, stream>>>(X, Xb, W, Wb);

    dim3 g1(OUT3 / 128, NROWS / 128);           // 24 x 32 = 768 blocks
    qkv_gemm_mfma<<<g1, 256, 0, stream>>>(Xb, Wb, bias, qb, kb, vtb);

    dim3 g2(S_SEQ / 128, 32);                   // 16 x 32 = 512 blocks
    attn32_kernel<<<g2, 256, 0, stream>>>(qb, kb, vtb, out);
}